// Round 11
// baseline (1275.634 us; speedup 1.0000x reference)
//
#include <hip/hip_runtime.h>
#include <cstdint>

#pragma STDC FP_CONTRACT OFF

// ---------------------------------------------------------------------------
// GridCLIP forward: hash-grid encode (16 levels x 8) -> MLP 128->256->256->1024
// Round 11: GEMMs restructured for the tiny-K/huge-M shape. Old: k-loop with
// a vmcnt(0)-drain barrier per iteration (2-4 iters -> drain-dominated,
// ~270 TF effective). New: stage the whole A-tile once (flat contiguous
// global_load_lds, ONE barrier), hoist A-fragments into registers, then
// stream N with no barriers: per 16-col chunk read B-fragments straight from
// the L2-resident 0.5MB weights (global->reg, named 2-deep prefetch), 16
// MFMA, store. Same MFMA k-order -> bit-identical output to R10.
// Encode unchanged (R8-proven XLA div->mul-reciprocal chain).
// ---------------------------------------------------------------------------

typedef _Float16 f16;
typedef __attribute__((ext_vector_type(8))) _Float16 f16x8;
typedef __attribute__((ext_vector_type(4))) float f32x4;

#define ACT_SCALE 4096.0f
#define INV_ACT_SCALE (1.0f / 4096.0f)

// global(AS1) -> LDS(AS3) direct 16B load
__device__ __forceinline__ void gld16(const void* g, void* l) {
  __builtin_amdgcn_global_load_lds(
      (const __attribute__((address_space(1))) void*)(uintptr_t)g,
      (__attribute__((address_space(3))) void*)(uint32_t)(uintptr_t)l,
      16, 0, 0);
}

// ---------------- grid encode (bit-exact XLA chain, f16-scaled output) -----
__global__ __launch_bounds__(256) void grid_encode_kernel(
    const float* __restrict__ x, const float* __restrict__ emb,
    f16* __restrict__ gh, int p0, int npts)
{
#pragma clang fp contract(off)
  int g = blockIdx.x * blockDim.x + threadIdx.x;
  if (g >= npts * 16) return;
  int pl = g >> 4;           // point within chunk
  int l  = g & 15;           // level
  int p  = p0 + pl;          // global point

  float x0 = x[3 * p + 0];
  float x1 = x[3 * p + 1];
  float x2 = x[3 * p + 2];

  // XLA chain: t = (x+10) * 0.05f (div->mul-reciprocal) ; u = (t+1) * 0.5
  float t0 = (x0 + 10.0f) * 0.05f;
  float t1 = (x1 + 10.0f) * 0.05f;
  float t2 = (x2 + 10.0f) * 0.05f;
  asm volatile("" : "+v"(t0), "+v"(t1), "+v"(t2));
  float u0 = (t0 + 1.0f) * 0.5f;
  float u1 = (t1 + 1.0f) * 0.5f;
  float u2 = (t2 + 1.0f) * 0.5f;
  asm volatile("" : "+v"(u0), "+v"(u1), "+v"(u2));

  float scale = (float)((16 << l) - 1);
  float pos0 = u0 * scale + 0.5f;
  float pos1 = u1 * scale + 0.5f;
  float pos2 = u2 * scale + 0.5f;

  float fb0 = floorf(pos0), fb1 = floorf(pos1), fb2 = floorf(pos2);
  float f0 = pos0 - fb0;
  float f1 = pos1 - fb1;
  float f2 = pos2 - fb2;
  uint32_t px = (uint32_t)fb0, py = (uint32_t)fb1, pz = (uint32_t)fb2;

  uint32_t mask = (l < 3) ? ((4096u << (3 * l)) - 1u) : 2097151u;
  uint32_t off;
  if (l == 0)      off = 0u;
  else if (l == 1) off = 4096u;
  else if (l == 2) off = 36864u;
  else             off = 299008u + (uint32_t)(l - 3) * 2097152u;

  float wx[2] = {1.0f - f0, f0};
  float wy[2] = {1.0f - f1, f1};
  float wz[2] = {1.0f - f2, f2};

  float acc[8];
#pragma unroll
  for (int j = 0; j < 8; ++j) acc[j] = 0.0f;

#pragma unroll
  for (int c = 0; c < 8; ++c) {
    uint32_t cx = px + (uint32_t)(c & 1);
    uint32_t cy = py + (uint32_t)((c >> 1) & 1);
    uint32_t cz = pz + (uint32_t)((c >> 2) & 1);
    float w = wx[c & 1] * wy[(c >> 1) & 1] * wz[(c >> 2) & 1];
    uint32_t h = cx ^ (cy * 2654435761u) ^ (cz * 805459861u);
    uint32_t idx = (h & mask) + off;
    const float4* e = (const float4*)(emb + (size_t)idx * 8);
    float4 e0 = e[0];
    float4 e1 = e[1];
    float m0 = w * e0.x, m1 = w * e0.y, m2 = w * e0.z, m3 = w * e0.w;
    float m4 = w * e1.x, m5 = w * e1.y, m6 = w * e1.z, m7 = w * e1.w;
    asm volatile("" : "+v"(m0), "+v"(m1), "+v"(m2), "+v"(m3),
                      "+v"(m4), "+v"(m5), "+v"(m6), "+v"(m7));
    acc[0] += m0; acc[1] += m1; acc[2] += m2; acc[3] += m3;
    acc[4] += m4; acc[5] += m5; acc[6] += m6; acc[7] += m7;
  }

  f16x8 o;
#pragma unroll
  for (int j = 0; j < 8; ++j) o[j] = (f16)(acc[j] * ACT_SCALE);
  *(f16x8*)&gh[(size_t)pl * 128 + l * 8] = o;
}

// ---------------- weight prep: f32 [K][N] -> f16 [N][K] --------------------
template <int K, int N>
__global__ __launch_bounds__(256) void prep_w(
    const float* __restrict__ W, f16* __restrict__ Wt)
{
  int i = blockIdx.x * 256 + threadIdx.x;  // i = n*K + k
  if (i >= N * K) return;
  int n = i / K, k = i - n * K;
  Wt[i] = (f16)W[(size_t)k * N + n];
}

// ---------------- K-resident MFMA GEMM -------------------------------------
// C[M,N] = act(A[M,K] @ Wt[N,K]^T + bias). BM=128 rows/block, 4 waves, each
// wave owns 32 rows (2 row-frags). Whole A-tile staged once (flat gld16, one
// barrier), A-fragments hoisted to registers, N streamed in 16-col chunks
// with B-fragments read global->reg from L2-hot Wt (2-deep named prefetch).
// ACT=1: f16 scaled relu out. SPLIT=1: f32 out, cols [0,512)->label block,
// [512,1024)->image block.
template <int K, int N, int ACT, int SPLIT>
__global__ __launch_bounds__(256, 2) void mlp_gemm(
    const f16* __restrict__ A, const f16* __restrict__ Wt,
    const float* __restrict__ bias, void* __restrict__ Cout,
    int rowBase, int nTotal)
{
  constexpr int BM = 128;
  constexpr int KF = K / 32;   // k-fragments per row
  constexpr int NJ = N / 16;   // 16-col chunks (16 or 64; always even)
  __shared__ alignas(16) f16 As[BM * K];

  const int tid  = threadIdx.x;
  const int lane = tid & 63;
  const int wid  = tid >> 6;       // 0..3
  const int bm   = blockIdx.x * BM;

  // ---- stage whole A tile: contiguous BM*K f16, dest = uniform + lane*16B
  const f16* Ablk = A + (size_t)bm * K;
  for (int off = tid * 8; off < BM * K; off += 256 * 8)
    gld16(&Ablk[off], &As[off]);
  __syncthreads();  // single vmcnt drain per block

  const int lr   = lane & 15;      // frag row (A) / col (B,C)
  const int lkg  = lane >> 4;      // k-granule 0..3
  const int wrow = wid * 32;       // wave's first row in tile

  // ---- hoist A fragments to registers (one-time; conflicts acceptable)
  f16x8 af[2][KF];
#pragma unroll
  for (int i = 0; i < 2; ++i)
#pragma unroll
    for (int f = 0; f < KF; ++f)
      af[i][f] = *(const f16x8*)&As[(wrow + i * 16 + lr) * K + f * 32 + lkg * 8];

  // ---- B fragment loader (global, L2-resident weights)
  auto loadB = [&](f16x8* bf, int j) {
    const f16* wp = Wt + (size_t)(j * 16 + lr) * K + lkg * 8;
#pragma unroll
    for (int f = 0; f < KF; ++f) bf[f] = *(const f16x8*)(wp + f * 32);
  };

  // ---- compute + store one 16-col chunk
  auto tile = [&](const f16x8* bf, int j) {
    const int col = j * 16 + lr;
    const float bv = bias[col];
#pragma unroll
    for (int i = 0; i < 2; ++i) {
      f32x4 a = (f32x4){0.f, 0.f, 0.f, 0.f};
#pragma unroll
      for (int f = 0; f < KF; ++f)
        a = __builtin_amdgcn_mfma_f32_16x16x32_f16(af[i][f], bf[f], a, 0, 0, 0);
      const int row0 = bm + wrow + i * 16 + (lane >> 4) * 4;
#pragma unroll
      for (int q = 0; q < 4; ++q) {
        float v = a[q];
        const int row = row0 + q;
        if (ACT) {
          v = fmaxf(v + bv * ACT_SCALE, 0.0f);
          ((f16*)Cout)[(size_t)row * N + col] = (f16)v;
        } else {
          v = v * INV_ACT_SCALE + bv;
          size_t grow = (size_t)(rowBase + row);
          float* dst = (col < 512)
                           ? ((float*)Cout + grow * 512 + col)
                           : ((float*)Cout + (size_t)nTotal * 512 + grow * 512 +
                              (col - 512));
          *dst = v;
        }
      }
    }
  };

  // ---- N-stream: 2-deep named prefetch, zero barriers
  f16x8 bfA[KF], bfB[KF];
  loadB(bfA, 0);
  for (int j = 0; j < NJ; j += 2) {
    loadB(bfB, j + 1);
    tile(bfA, j);
    if (j + 2 < NJ) loadB(bfA, j + 2);
    tile(bfB, j + 1);
  }
}

// ---------------- launch ----------------
extern "C" void kernel_launch(void* const* d_in, const int* in_sizes, int n_in,
                              void* d_out, int out_size, void* d_ws, size_t ws_size,
                              hipStream_t stream)
{
  const float* x   = (const float*)d_in[0];
  const float* emb = (const float*)d_in[1];
  const float* W1  = (const float*)d_in[2];
  const float* b1  = (const float*)d_in[3];
  const float* W2  = (const float*)d_in[4];
  const float* b2  = (const float*)d_in[5];
  const float* W3  = (const float*)d_in[6];
  const float* b3  = (const float*)d_in[7];
  float* out = (float*)d_out;

  const int NPTS = in_sizes[0] / 3;  // 262144

  // ws layout: Wt1 | Wt2 | Wt3 | gh(f16) | h1(f16) | h2(f16)
  f16* Wt1 = (f16*)d_ws;                 // 128*256
  f16* Wt2 = Wt1 + 128 * 256;            // 256*256
  f16* Wt3 = Wt2 + 256 * 256;            // 256*1024
  f16* wsAct = Wt3 + 256 * 1024;
  const size_t wtBytes = (size_t)(128 * 256 + 256 * 256 + 256 * 1024) * sizeof(f16);

  // chunk rows: gh C*128 f16 + h1 C*256 f16 + h2 C*256 f16 = 1280 B/row
  long long cmax = (long long)((ws_size - wtBytes) / 1280);
  int C = (int)((cmax / 128) * 128);
  if (C > NPTS) C = NPTS;
  if (C < 128) C = 128;

  f16* gh = wsAct;
  f16* h1 = gh + (size_t)C * 128;
  f16* h2 = h1 + (size_t)C * 256;

  prep_w<128, 256><<<(128 * 256 + 255) / 256, 256, 0, stream>>>(W1, Wt1);
  prep_w<256, 256><<<(256 * 256 + 255) / 256, 256, 0, stream>>>(W2, Wt2);
  prep_w<256, 1024><<<(256 * 1024 + 255) / 256, 256, 0, stream>>>(W3, Wt3);

  for (int p0 = 0; p0 < NPTS; p0 += C) {
    int cur = (NPTS - p0 < C) ? (NPTS - p0) : C;

    int nthr = cur * 16;
    grid_encode_kernel<<<(nthr + 255) / 256, 256, 0, stream>>>(x, emb, gh, p0, cur);

    mlp_gemm<128, 256, 1, 0><<<cur / 128, 256, 0, stream>>>(gh, Wt1, b1, h1, p0, NPTS);
    mlp_gemm<256, 256, 1, 0><<<cur / 128, 256, 0, stream>>>(h1, Wt2, b2, h2, p0, NPTS);
    mlp_gemm<256, 1024, 0, 1><<<cur / 128, 256, 0, stream>>>(h2, Wt3, b3, out, p0, NPTS);
  }
}

// Round 12
// 1057.755 us; speedup vs baseline: 1.2060x; 1.2060x over previous
//
#include <hip/hip_runtime.h>
#include <cstdint>

#pragma STDC FP_CONTRACT OFF

// ---------------------------------------------------------------------------
// GridCLIP forward: hash-grid encode (16 levels x 8) -> MLP 128->256->256->1024
// Round 12: revert R11's latency-bound N-streaming; back to R10's
// global_load_lds + granule-swizzle GEMM, now with DOUBLE-BUFFERED K-tiles
// (T3-minimum 2-phase): issue next tile's global_load_lds before computing
// the current tile, one barrier per iteration drains it -> staging latency
// hides under MFMA. Same k-order/swizzle => bit-identical to R10's pass.
// Encode unchanged (R8-proven XLA div->mul-reciprocal chain).
// ---------------------------------------------------------------------------

typedef _Float16 f16;
typedef __attribute__((ext_vector_type(8))) _Float16 f16x8;
typedef __attribute__((ext_vector_type(4))) float f32x4;

#define ACT_SCALE 4096.0f
#define INV_ACT_SCALE (1.0f / 4096.0f)

// global(AS1) -> LDS(AS3) direct 16B load
__device__ __forceinline__ void gld16(const void* g, void* l) {
  __builtin_amdgcn_global_load_lds(
      (const __attribute__((address_space(1))) void*)(uintptr_t)g,
      (__attribute__((address_space(3))) void*)(uint32_t)(uintptr_t)l,
      16, 0, 0);
}

// ---------------- grid encode (bit-exact XLA chain, f16-scaled output) -----
__global__ __launch_bounds__(256) void grid_encode_kernel(
    const float* __restrict__ x, const float* __restrict__ emb,
    f16* __restrict__ gh, int p0, int npts)
{
#pragma clang fp contract(off)
  int g = blockIdx.x * blockDim.x + threadIdx.x;
  if (g >= npts * 16) return;
  int pl = g >> 4;           // point within chunk
  int l  = g & 15;           // level
  int p  = p0 + pl;          // global point

  float x0 = x[3 * p + 0];
  float x1 = x[3 * p + 1];
  float x2 = x[3 * p + 2];

  // XLA chain: t = (x+10) * 0.05f (div->mul-reciprocal) ; u = (t+1) * 0.5
  float t0 = (x0 + 10.0f) * 0.05f;
  float t1 = (x1 + 10.0f) * 0.05f;
  float t2 = (x2 + 10.0f) * 0.05f;
  asm volatile("" : "+v"(t0), "+v"(t1), "+v"(t2));
  float u0 = (t0 + 1.0f) * 0.5f;
  float u1 = (t1 + 1.0f) * 0.5f;
  float u2 = (t2 + 1.0f) * 0.5f;
  asm volatile("" : "+v"(u0), "+v"(u1), "+v"(u2));

  float scale = (float)((16 << l) - 1);
  float pos0 = u0 * scale + 0.5f;
  float pos1 = u1 * scale + 0.5f;
  float pos2 = u2 * scale + 0.5f;

  float fb0 = floorf(pos0), fb1 = floorf(pos1), fb2 = floorf(pos2);
  float f0 = pos0 - fb0;
  float f1 = pos1 - fb1;
  float f2 = pos2 - fb2;
  uint32_t px = (uint32_t)fb0, py = (uint32_t)fb1, pz = (uint32_t)fb2;

  uint32_t mask = (l < 3) ? ((4096u << (3 * l)) - 1u) : 2097151u;
  uint32_t off;
  if (l == 0)      off = 0u;
  else if (l == 1) off = 4096u;
  else if (l == 2) off = 36864u;
  else             off = 299008u + (uint32_t)(l - 3) * 2097152u;

  float wx[2] = {1.0f - f0, f0};
  float wy[2] = {1.0f - f1, f1};
  float wz[2] = {1.0f - f2, f2};

  float acc[8];
#pragma unroll
  for (int j = 0; j < 8; ++j) acc[j] = 0.0f;

#pragma unroll
  for (int c = 0; c < 8; ++c) {
    uint32_t cx = px + (uint32_t)(c & 1);
    uint32_t cy = py + (uint32_t)((c >> 1) & 1);
    uint32_t cz = pz + (uint32_t)((c >> 2) & 1);
    float w = wx[c & 1] * wy[(c >> 1) & 1] * wz[(c >> 2) & 1];
    uint32_t h = cx ^ (cy * 2654435761u) ^ (cz * 805459861u);
    uint32_t idx = (h & mask) + off;
    const float4* e = (const float4*)(emb + (size_t)idx * 8);
    float4 e0 = e[0];
    float4 e1 = e[1];
    float m0 = w * e0.x, m1 = w * e0.y, m2 = w * e0.z, m3 = w * e0.w;
    float m4 = w * e1.x, m5 = w * e1.y, m6 = w * e1.z, m7 = w * e1.w;
    asm volatile("" : "+v"(m0), "+v"(m1), "+v"(m2), "+v"(m3),
                      "+v"(m4), "+v"(m5), "+v"(m6), "+v"(m7));
    acc[0] += m0; acc[1] += m1; acc[2] += m2; acc[3] += m3;
    acc[4] += m4; acc[5] += m5; acc[6] += m6; acc[7] += m7;
  }

  f16x8 o;
#pragma unroll
  for (int j = 0; j < 8; ++j) o[j] = (f16)(acc[j] * ACT_SCALE);
  *(f16x8*)&gh[(size_t)pl * 128 + l * 8] = o;
}

// ---------------- weight prep: f32 [K][N] -> f16 [N][K] --------------------
template <int K, int N>
__global__ __launch_bounds__(256) void prep_w(
    const float* __restrict__ W, f16* __restrict__ Wt)
{
  int i = blockIdx.x * 256 + threadIdx.x;  // i = n*K + k
  if (i >= N * K) return;
  int n = i / K, k = i - n * K;
  Wt[i] = (f16)W[(size_t)k * N + n];
}

// ---------------- f16 MFMA GEMM, double-buffered K-tiles -------------------
// C[M,N] = act(A[M,K] @ Wt[N,K]^T + bias). BM=BN=128, BK=64, 4 waves (2x2),
// wave tile 64x64 = 4x4 frags of 16x16x32. global_load_lds staging into
// linear LDS, granule swizzle g^=(row&7) on source+read (rule 21 both-sides).
// 2-phase: stage tile t+1 into buf^1 BEFORE computing tile t; one barrier per
// iter drains it (staging latency hides under MFMA).
// ACT=1: f16 scaled relu out. SPLIT=1: f32 out, cols [0,512)->label block,
// [512,1024)->image block.
template <int K, int N, int ACT, int SPLIT>
__global__ __launch_bounds__(256) void mfma_gemm(
    const f16* __restrict__ A, const f16* __restrict__ Wt,
    const float* __restrict__ bias, void* __restrict__ Cout,
    int rowBase, int nTotal)
{
  constexpr int BM = 128, BK = 64, KT = K / BK;
  __shared__ alignas(16) f16 As[2][BM * BK];
  __shared__ alignas(16) f16 Bs[2][BM * BK];

  const int tid  = threadIdx.x;
  const int lane = tid & 63;
  const int wid  = tid >> 6;     // 0..3
  const int wr   = wid >> 1;     // wave row 0..1
  const int wc   = wid & 1;      // wave col 0..1
  const int bm   = blockIdx.x * BM;
  const int bn   = blockIdx.y * BM;

  const int lr  = lane & 15;         // fragment row (A) / col (B/C)
  const int lkg = lane >> 4;         // k-granule within fragment (0..3)

  f32x4 acc[4][4];
#pragma unroll
  for (int i = 0; i < 4; ++i)
#pragma unroll
    for (int j = 0; j < 4; ++j) acc[i][j] = (f32x4){0.f, 0.f, 0.f, 0.f};

  // staging geometry (per wave, per instruction i: 8 rows x 64 f16)
  const int srow_off = lane >> 3;          // row within 8-row group
  const int sg       = lane & 7;           // dest granule

  auto stage = [&](int buf, int kt) {
#pragma unroll
    for (int i = 0; i < 4; ++i) {
      const int r0  = wid * 32 + i * 8;
      const int row = r0 + srow_off;
      const int gs  = sg ^ (row & 7);      // inverse-swizzled source granule
      gld16(&A[(size_t)(bm + row) * K + kt * BK + gs * 8], &As[buf][r0 * BK]);
      gld16(&Wt[(size_t)(bn + row) * K + kt * BK + gs * 8], &Bs[buf][r0 * BK]);
    }
  };

  stage(0, 0);
  __syncthreads();  // prologue drain

  for (int kt = 0; kt < KT; ++kt) {
    const int cur = kt & 1;
    if (kt + 1 < KT) stage(cur ^ 1, kt + 1);  // async into other buffer

#pragma unroll
    for (int kk = 0; kk < 2; ++kk) {
      f16x8 af[4], bf[4];
#pragma unroll
      for (int i = 0; i < 4; ++i) {
        const int ar = wr * 64 + i * 16 + lr;
        const int br = wc * 64 + i * 16 + lr;
        af[i] = *(const f16x8*)&As[cur][ar * BK + ((kk * 4 + lkg) ^ (ar & 7)) * 8];
        bf[i] = *(const f16x8*)&Bs[cur][br * BK + ((kk * 4 + lkg) ^ (br & 7)) * 8];
      }
#pragma unroll
      for (int i = 0; i < 4; ++i)
#pragma unroll
        for (int j = 0; j < 4; ++j)
          acc[i][j] = __builtin_amdgcn_mfma_f32_16x16x32_f16(
              af[i], bf[j], acc[i][j], 0, 0, 0);
    }
    __syncthreads();  // drains next-tile staging (vmcnt) + all lds reads
  }

  // epilogue: C/D frag mapping col=lane&15, row=(lane>>4)*4+q (m89-verified)
  const int orow0 = bm + wr * 64;
  const int ocol0 = bn + wc * 64;
#pragma unroll
  for (int i = 0; i < 4; ++i) {
#pragma unroll
    for (int j = 0; j < 4; ++j) {
      int col = ocol0 + j * 16 + lr;
      float bv = bias[col];
#pragma unroll
      for (int q = 0; q < 4; ++q) {
        int row = orow0 + i * 16 + (lane >> 4) * 4 + q;
        float v = acc[i][j][q];
        if (ACT) {
          v = fmaxf(v + bv * ACT_SCALE, 0.0f);
          ((f16*)Cout)[(size_t)row * N + col] = (f16)v;
        } else {
          v = v * INV_ACT_SCALE + bv;
          size_t grow = (size_t)(rowBase + row);
          float* dst = (col < 512)
                           ? ((float*)Cout + grow * 512 + col)
                           : ((float*)Cout + (size_t)nTotal * 512 + grow * 512 +
                              (col - 512));
          *dst = v;
        }
      }
    }
  }
}

// ---------------- launch ----------------
extern "C" void kernel_launch(void* const* d_in, const int* in_sizes, int n_in,
                              void* d_out, int out_size, void* d_ws, size_t ws_size,
                              hipStream_t stream)
{
  const float* x   = (const float*)d_in[0];
  const float* emb = (const float*)d_in[1];
  const float* W1  = (const float*)d_in[2];
  const float* b1  = (const float*)d_in[3];
  const float* W2  = (const float*)d_in[4];
  const float* b2  = (const float*)d_in[5];
  const float* W3  = (const float*)d_in[6];
  const float* b3  = (const float*)d_in[7];
  float* out = (float*)d_out;

  const int NPTS = in_sizes[0] / 3;  // 262144

  // ws layout: Wt1 | Wt2 | Wt3 | gh(f16) | h1(f16) | h2(f16)
  f16* Wt1 = (f16*)d_ws;                 // 128*256
  f16* Wt2 = Wt1 + 128 * 256;            // 256*256
  f16* Wt3 = Wt2 + 256 * 256;            // 256*1024
  f16* wsAct = Wt3 + 256 * 1024;
  const size_t wtBytes = (size_t)(128 * 256 + 256 * 256 + 256 * 1024) * sizeof(f16);

  // chunk rows: gh C*128 f16 + h1 C*256 f16 + h2 C*256 f16 = 1280 B/row
  long long cmax = (long long)((ws_size - wtBytes) / 1280);
  int C = (int)((cmax / 128) * 128);
  if (C > NPTS) C = NPTS;
  if (C < 128) C = 128;

  f16* gh = wsAct;
  f16* h1 = gh + (size_t)C * 128;
  f16* h2 = h1 + (size_t)C * 256;

  prep_w<128, 256><<<(128 * 256 + 255) / 256, 256, 0, stream>>>(W1, Wt1);
  prep_w<256, 256><<<(256 * 256 + 255) / 256, 256, 0, stream>>>(W2, Wt2);
  prep_w<256, 1024><<<(256 * 1024 + 255) / 256, 256, 0, stream>>>(W3, Wt3);

  for (int p0 = 0; p0 < NPTS; p0 += C) {
    int cur = (NPTS - p0 < C) ? (NPTS - p0) : C;

    int nthr = cur * 16;
    grid_encode_kernel<<<(nthr + 255) / 256, 256, 0, stream>>>(x, emb, gh, p0, cur);

    dim3 g1(cur / 128, 2);
    mfma_gemm<128, 256, 1, 0><<<g1, 256, 0, stream>>>(gh, Wt1, b1, h1, p0, NPTS);

    dim3 g2(cur / 128, 2);
    mfma_gemm<256, 256, 1, 0><<<g2, 256, 0, stream>>>(h1, Wt2, b2, h2, p0, NPTS);

    dim3 g3(cur / 128, 8);
    mfma_gemm<256, 1024, 0, 1><<<g3, 256, 0, stream>>>(h2, Wt3, b3, out, p0, NPTS);
  }
}

// Round 13
// 867.616 us; speedup vs baseline: 1.4703x; 1.2192x over previous
//
#include <hip/hip_runtime.h>
#include <cstdint>

#pragma STDC FP_CONTRACT OFF

// ---------------------------------------------------------------------------
// GridCLIP forward: hash-grid encode (16 levels x 8) -> MLP 128->256->256->1024
// Round 13: fuse gemm2+gemm3. Per 128-row block (512 thr, 8 waves):
//   phase 2: h2 = relu(h1 @ W2 + b2*S), h1 staged dbuf via global_load_lds
//            (granule swizzle, rule 21), W2 in REGISTERS (frag-ordered copy,
//            coalesced one-time load), h2 -> swizzled 64KB LDS buffer.
//   phase 3: out = h2(LDS) @ W3 + b3, A-frags hoisted once to regs, W3
//            streamed in 32-col chunks dbuf'd through the freed staging bufs.
// h2 never touches HBM/LLC (was: 128 MB write + 8x128 MB re-read).
// K-order and f32 accumulation identical to R12 -> bit-identical output.
// Encode + gemm1 unchanged (R8-proven math; R12 structure).
// ---------------------------------------------------------------------------

typedef _Float16 f16;
typedef __attribute__((ext_vector_type(8))) _Float16 f16x8;
typedef __attribute__((ext_vector_type(4))) float f32x4;

#define ACT_SCALE 4096.0f
#define INV_ACT_SCALE (1.0f / 4096.0f)

__device__ __forceinline__ void gld16(const void* g, void* l) {
  __builtin_amdgcn_global_load_lds(
      (const __attribute__((address_space(1))) void*)(uintptr_t)g,
      (__attribute__((address_space(3))) void*)(uint32_t)(uintptr_t)l,
      16, 0, 0);
}

// ---------------- grid encode (bit-exact XLA chain, f16-scaled output) -----
__global__ __launch_bounds__(256) void grid_encode_kernel(
    const float* __restrict__ x, const float* __restrict__ emb,
    f16* __restrict__ gh, int p0, int npts)
{
#pragma clang fp contract(off)
  int g = blockIdx.x * blockDim.x + threadIdx.x;
  if (g >= npts * 16) return;
  int pl = g >> 4;
  int l  = g & 15;
  int p  = p0 + pl;

  float x0 = x[3 * p + 0];
  float x1 = x[3 * p + 1];
  float x2 = x[3 * p + 2];

  float t0 = (x0 + 10.0f) * 0.05f;
  float t1 = (x1 + 10.0f) * 0.05f;
  float t2 = (x2 + 10.0f) * 0.05f;
  asm volatile("" : "+v"(t0), "+v"(t1), "+v"(t2));
  float u0 = (t0 + 1.0f) * 0.5f;
  float u1 = (t1 + 1.0f) * 0.5f;
  float u2 = (t2 + 1.0f) * 0.5f;
  asm volatile("" : "+v"(u0), "+v"(u1), "+v"(u2));

  float scale = (float)((16 << l) - 1);
  float pos0 = u0 * scale + 0.5f;
  float pos1 = u1 * scale + 0.5f;
  float pos2 = u2 * scale + 0.5f;

  float fb0 = floorf(pos0), fb1 = floorf(pos1), fb2 = floorf(pos2);
  float f0 = pos0 - fb0;
  float f1 = pos1 - fb1;
  float f2 = pos2 - fb2;
  uint32_t px = (uint32_t)fb0, py = (uint32_t)fb1, pz = (uint32_t)fb2;

  uint32_t mask = (l < 3) ? ((4096u << (3 * l)) - 1u) : 2097151u;
  uint32_t off;
  if (l == 0)      off = 0u;
  else if (l == 1) off = 4096u;
  else if (l == 2) off = 36864u;
  else             off = 299008u + (uint32_t)(l - 3) * 2097152u;

  float wx[2] = {1.0f - f0, f0};
  float wy[2] = {1.0f - f1, f1};
  float wz[2] = {1.0f - f2, f2};

  float acc[8];
#pragma unroll
  for (int j = 0; j < 8; ++j) acc[j] = 0.0f;

#pragma unroll
  for (int c = 0; c < 8; ++c) {
    uint32_t cx = px + (uint32_t)(c & 1);
    uint32_t cy = py + (uint32_t)((c >> 1) & 1);
    uint32_t cz = pz + (uint32_t)((c >> 2) & 1);
    float w = wx[c & 1] * wy[(c >> 1) & 1] * wz[(c >> 2) & 1];
    uint32_t h = cx ^ (cy * 2654435761u) ^ (cz * 805459861u);
    uint32_t idx = (h & mask) + off;
    const float4* e = (const float4*)(emb + (size_t)idx * 8);
    float4 e0 = e[0];
    float4 e1 = e[1];
    float m0 = w * e0.x, m1 = w * e0.y, m2 = w * e0.z, m3 = w * e0.w;
    float m4 = w * e1.x, m5 = w * e1.y, m6 = w * e1.z, m7 = w * e1.w;
    asm volatile("" : "+v"(m0), "+v"(m1), "+v"(m2), "+v"(m3),
                      "+v"(m4), "+v"(m5), "+v"(m6), "+v"(m7));
    acc[0] += m0; acc[1] += m1; acc[2] += m2; acc[3] += m3;
    acc[4] += m4; acc[5] += m5; acc[6] += m6; acc[7] += m7;
  }

  f16x8 o;
#pragma unroll
  for (int j = 0; j < 8; ++j) o[j] = (f16)(acc[j] * ACT_SCALE);
  *(f16x8*)&gh[(size_t)pl * 128 + l * 8] = o;
}

// ---------------- weight preps ---------------------------------------------
// W -> f16 transposed [N][K]
template <int K, int N>
__global__ __launch_bounds__(256) void prep_w(
    const float* __restrict__ W, f16* __restrict__ Wt)
{
  int i = blockIdx.x * 256 + threadIdx.x;
  if (i >= N * K) return;
  int n = i / K, k = i - n * K;
  Wt[i] = (f16)W[(size_t)k * N + n];
}

// W2 (256x256) -> fragment-ordered f16: granule (q,kg,lr), q=n>>4, kg=k>>3,
// lr=n&15. Lane (lr,lkg) loading frag (q,f) reads consecutive granules.
__global__ __launch_bounds__(256) void prep_w2f(
    const float* __restrict__ W2, f16* __restrict__ Wf2)
{
  int i = blockIdx.x * 256 + threadIdx.x;  // 0..65535
  if (i >= 256 * 256) return;
  int e  = i & 7;
  int lr = (i >> 3) & 15;
  int kg = (i >> 7) & 31;
  int q  = i >> 12;
  int n = q * 16 + lr;
  int k = kg * 8 + e;
  Wf2[i] = (f16)W2[(size_t)k * 256 + n];
}

// ---------------- gemm1 (R12 structure, unchanged) -------------------------
template <int K, int N>
__global__ __launch_bounds__(256) void mfma_gemm1(
    const f16* __restrict__ A, const f16* __restrict__ Wt,
    const float* __restrict__ bias, f16* __restrict__ Cout)
{
  constexpr int BM = 128, BK = 64, KT = K / BK;
  __shared__ alignas(16) f16 As[2][BM * BK];
  __shared__ alignas(16) f16 Bs[2][BM * BK];

  const int tid  = threadIdx.x;
  const int lane = tid & 63;
  const int wid  = tid >> 6;
  const int wr   = wid >> 1;
  const int wc   = wid & 1;
  const int bm   = blockIdx.x * BM;
  const int bn   = blockIdx.y * BM;

  const int lr  = lane & 15;
  const int lkg = lane >> 4;

  f32x4 acc[4][4];
#pragma unroll
  for (int i = 0; i < 4; ++i)
#pragma unroll
    for (int j = 0; j < 4; ++j) acc[i][j] = (f32x4){0.f, 0.f, 0.f, 0.f};

  const int srow_off = lane >> 3;
  const int sg       = lane & 7;

  auto stage = [&](int buf, int kt) {
#pragma unroll
    for (int i = 0; i < 4; ++i) {
      const int r0  = wid * 32 + i * 8;
      const int row = r0 + srow_off;
      const int gs  = sg ^ (row & 7);
      gld16(&A[(size_t)(bm + row) * K + kt * BK + gs * 8], &As[buf][r0 * BK]);
      gld16(&Wt[(size_t)(bn + row) * K + kt * BK + gs * 8], &Bs[buf][r0 * BK]);
    }
  };

  stage(0, 0);
  __syncthreads();

  for (int kt = 0; kt < KT; ++kt) {
    const int cur = kt & 1;
    if (kt + 1 < KT) stage(cur ^ 1, kt + 1);
#pragma unroll
    for (int kk = 0; kk < 2; ++kk) {
      f16x8 af[4], bf[4];
#pragma unroll
      for (int i = 0; i < 4; ++i) {
        const int ar = wr * 64 + i * 16 + lr;
        const int br = wc * 64 + i * 16 + lr;
        af[i] = *(const f16x8*)&As[cur][ar * BK + ((kk * 4 + lkg) ^ (ar & 7)) * 8];
        bf[i] = *(const f16x8*)&Bs[cur][br * BK + ((kk * 4 + lkg) ^ (br & 7)) * 8];
      }
#pragma unroll
      for (int i = 0; i < 4; ++i)
#pragma unroll
        for (int j = 0; j < 4; ++j)
          acc[i][j] = __builtin_amdgcn_mfma_f32_16x16x32_f16(
              af[i], bf[j], acc[i][j], 0, 0, 0);
    }
    __syncthreads();
  }

  const int orow0 = bm + wr * 64;
  const int ocol0 = bn + wc * 64;
#pragma unroll
  for (int i = 0; i < 4; ++i)
#pragma unroll
    for (int j = 0; j < 4; ++j) {
      int col = ocol0 + j * 16 + lr;
      float bv = bias[col];
#pragma unroll
      for (int q = 0; q < 4; ++q) {
        int row = orow0 + i * 16 + lkg * 4 + q;
        float v = fmaxf(acc[i][j][q] + bv * ACT_SCALE, 0.0f);
        Cout[(size_t)row * N + col] = (f16)v;
      }
    }
}

// ---------------- fused gemm2+gemm3 ----------------------------------------
// 512 threads (8 waves). K1=256, NH=256, NO=1024.
__global__ __launch_bounds__(512) void fused_gemm23(
    const f16* __restrict__ h1, const f16* __restrict__ Wf2,
    const float* __restrict__ b2, const f16* __restrict__ Wt3,
    const float* __restrict__ b3, float* __restrict__ out,
    int rowBase, int nTotal)
{
  constexpr int K1 = 256;
  __shared__ alignas(16) f16 As2[2][8192];  // 2x16KB: h1 k-tiles / W3 chunks
  __shared__ alignas(16) f16 H2[128 * 256]; // 64KB swizzled h2

  const int tid  = threadIdx.x;
  const int lane = tid & 63;
  const int wid  = tid >> 6;      // 0..7
  const int bm   = blockIdx.x * 128;
  const int lr   = lane & 15;
  const int lkg  = lane >> 4;     // 0..3

  // ===== phase 2: h2 = relu(h1 @ W2 + b2*S) =====
  const int rowg = wid >> 2;      // 0..1 (64-row groups)
  const int colg = wid & 3;       // 0..3 (64-col groups)

  // W2 fragments -> registers (coalesced from frag-ordered Wf2, one-time)
  f16x8 bf_all[4][8];
#pragma unroll
  for (int j = 0; j < 4; ++j)
#pragma unroll
    for (int f = 0; f < 8; ++f)
      bf_all[j][f] = *(const f16x8*)&Wf2[(((colg * 4 + j) * 32 + f * 4 + lkg) * 16 + lr) * 8];

  // h1 k-tile staging: 1024 granules, 2 per thread, linear dest,
  // inverse-swizzled source (rule 21)
  auto stage2 = [&](int buf, int kt) {
#pragma unroll
    for (int s = 0; s < 2; ++s) {
      const int gbase = wid * 64 + s * 512;       // uniform per wave
      const int g     = gbase + lane;
      const int row   = g >> 3;
      const int gs    = (g & 7) ^ (row & 7);
      gld16(&h1[(size_t)(bm + row) * K1 + kt * 64 + gs * 8],
            &As2[buf][gbase * 8]);
    }
  };

  f32x4 acc[4][4];
#pragma unroll
  for (int i = 0; i < 4; ++i)
#pragma unroll
    for (int j = 0; j < 4; ++j) acc[i][j] = (f32x4){0.f, 0.f, 0.f, 0.f};

  stage2(0, 0);
  __syncthreads();

#pragma unroll
  for (int kt = 0; kt < 4; ++kt) {
    const int cur = kt & 1;
    if (kt + 1 < 4) stage2(cur ^ 1, kt + 1);
#pragma unroll
    for (int kk = 0; kk < 2; ++kk) {
      f16x8 af[4];
#pragma unroll
      for (int i = 0; i < 4; ++i) {
        const int ar = rowg * 64 + i * 16 + lr;
        af[i] = *(const f16x8*)&As2[cur][ar * 64 + ((kk * 4 + lkg) ^ (ar & 7)) * 8];
      }
#pragma unroll
      for (int i = 0; i < 4; ++i)
#pragma unroll
        for (int j = 0; j < 4; ++j)
          acc[i][j] = __builtin_amdgcn_mfma_f32_16x16x32_f16(
              af[i], bf_all[j][kt * 2 + kk], acc[i][j], 0, 0, 0);
    }
    __syncthreads();
  }

  // h2 -> swizzled LDS (granule kg of row r stored at (kg&24)|((kg^r)&7))
#pragma unroll
  for (int i = 0; i < 4; ++i)
#pragma unroll
    for (int j = 0; j < 4; ++j) {
      const int col = colg * 64 + j * 16 + lr;
      const float bv = b2[col];
      const int kg = col >> 3, e = col & 7;
#pragma unroll
      for (int q = 0; q < 4; ++q) {
        const int row = rowg * 64 + i * 16 + lkg * 4 + q;
        const int kgs = (kg & 24) | ((kg ^ row) & 7);
        float v = fmaxf(acc[i][j][q] + bv * ACT_SCALE, 0.0f);
        H2[row * 256 + kgs * 8 + e] = (f16)v;
      }
    }

  // ===== phase 3: out = h2 @ W3 + b3 =====
  const int rowg3 = wid & 3;      // 0..3 (32-row groups)
  const int colg3 = wid >> 2;     // 0..1 (16-col groups within 32-col chunk)

  // W3 chunk staging: chunk c = 32 out-cols x 256 K = 1024 granules
  auto stage3 = [&](int buf, int c) {
#pragma unroll
    for (int s = 0; s < 2; ++s) {
      const int gbase = wid * 64 + s * 512;       // uniform per wave
      const int g     = gbase + lane;
      const int row   = g >> 5;                   // n within chunk (0..31)
      const int sg    = g & 31;
      const int gs    = (sg & 24) | ((sg ^ row) & 7);
      gld16(&Wt3[(size_t)(c * 32 + row) * 256 + gs * 8],
            &As2[buf][gbase * 8]);
    }
  };

  stage3(0, 0);
  __syncthreads();  // drains H2 writes + chunk-0 staging

  // hoist h2 A-frags (stable LDS) to registers
  f16x8 af3[2][8];
#pragma unroll
  for (int i = 0; i < 2; ++i)
#pragma unroll
    for (int f = 0; f < 8; ++f) {
      const int r  = rowg3 * 32 + i * 16 + lr;
      const int kg = f * 4 + lkg;
      const int kgs = (kg & 24) | ((kg ^ r) & 7);
      af3[i][f] = *(const f16x8*)&H2[r * 256 + kgs * 8];
    }

  for (int c = 0; c < 32; ++c) {
    const int buf = c & 1;
    if (c + 1 < 32) stage3(buf ^ 1, c + 1);

    f16x8 bf3[8];
#pragma unroll
    for (int f = 0; f < 8; ++f) {
      const int n  = colg3 * 16 + lr;
      const int kg = f * 4 + lkg;
      const int kgs = (kg & 24) | ((kg ^ n) & 7);
      bf3[f] = *(const f16x8*)&As2[buf][n * 256 + kgs * 8];
    }

    f32x4 a3[2];
#pragma unroll
    for (int i = 0; i < 2; ++i) {
      a3[i] = (f32x4){0.f, 0.f, 0.f, 0.f};
#pragma unroll
      for (int f = 0; f < 8; ++f)
        a3[i] = __builtin_amdgcn_mfma_f32_16x16x32_f16(af3[i][f], bf3[f], a3[i], 0, 0, 0);
    }

    const int col = c * 32 + colg3 * 16 + lr;
    const float bv = b3[col];
#pragma unroll
    for (int i = 0; i < 2; ++i) {
#pragma unroll
      for (int q = 0; q < 4; ++q) {
        const int row = bm + rowg3 * 32 + i * 16 + lkg * 4 + q;
        float v = a3[i][q] * INV_ACT_SCALE + bv;
        size_t grow = (size_t)(rowBase + row);
        float* dst = (col < 512)
                         ? (out + grow * 512 + col)
                         : (out + (size_t)nTotal * 512 + grow * 512 + (col - 512));
        *dst = v;
      }
    }
    __syncthreads();
  }
}

// ---------------- launch ----------------
extern "C" void kernel_launch(void* const* d_in, const int* in_sizes, int n_in,
                              void* d_out, int out_size, void* d_ws, size_t ws_size,
                              hipStream_t stream)
{
  const float* x   = (const float*)d_in[0];
  const float* emb = (const float*)d_in[1];
  const float* W1  = (const float*)d_in[2];
  const float* b1  = (const float*)d_in[3];
  const float* W2  = (const float*)d_in[4];
  const float* b2  = (const float*)d_in[5];
  const float* W3  = (const float*)d_in[6];
  const float* b3  = (const float*)d_in[7];
  float* out = (float*)d_out;

  const int NPTS = in_sizes[0] / 3;  // 262144

  // ws layout: Wt1 | Wf2 | Wt3 | gh(f16) | h1(f16)
  f16* Wt1 = (f16*)d_ws;                 // 128*256
  f16* Wf2 = Wt1 + 128 * 256;            // 256*256 frag-ordered
  f16* Wt3 = Wf2 + 256 * 256;            // 256*1024 transposed [N][K]
  f16* wsAct = Wt3 + 256 * 1024;
  const size_t wtBytes = (size_t)(128 * 256 + 256 * 256 + 256 * 1024) * sizeof(f16);

  // chunk rows: gh C*128 f16 + h1 C*256 f16 = 768 B/row
  long long cmax = (long long)((ws_size - wtBytes) / 768);
  int C = (int)((cmax / 128) * 128);
  if (C > NPTS) C = NPTS;
  if (C < 128) C = 128;

  f16* gh = wsAct;
  f16* h1 = gh + (size_t)C * 128;

  prep_w<128, 256><<<(128 * 256 + 255) / 256, 256, 0, stream>>>(W1, Wt1);
  prep_w2f<<<(256 * 256 + 255) / 256, 256, 0, stream>>>(W2, Wf2);
  prep_w<256, 1024><<<(256 * 1024 + 255) / 256, 256, 0, stream>>>(W3, Wt3);

  for (int p0 = 0; p0 < NPTS; p0 += C) {
    int cur = (NPTS - p0 < C) ? (NPTS - p0) : C;

    int nthr = cur * 16;
    grid_encode_kernel<<<(nthr + 255) / 256, 256, 0, stream>>>(x, emb, gh, p0, cur);

    dim3 g1(cur / 128, 2);
    mfma_gemm1<128, 256><<<g1, 256, 0, stream>>>(gh, Wt1, b1, h1);

    fused_gemm23<<<cur / 128, 512, 0, stream>>>(h1, Wf2, b2, Wt3, b3, out, p0, NPTS);
  }
}